// Round 6
// baseline (381.443 us; speedup 1.0000x reference)
//
#include <hip/hip_runtime.h>
#include <stdint.h>

#define SEQ   4096
#define NDIM  768
#define HD    64
#define NH    12
#define NBH   24        // 2 * 12
#define MTOT  8192      // 2 * 4096

// Attention K/V panel row stride in u16: 64 elems + 8 pad. Word stride
// 36 ≡ 4 (mod 32): 8-lane read phases full-cover the 32 banks -> conflict-free
// (R2/R4-verified, 0 SQ_LDS_BANK_CONFLICT).
#define PSTR 72

typedef short s8v __attribute__((ext_vector_type(8)));     // 8 bf16 (as shorts), 16B
typedef float f4v __attribute__((ext_vector_type(4)));
typedef float f16x __attribute__((ext_vector_type(16)));
typedef unsigned short u16;
typedef u16 u16x4 __attribute__((ext_vector_type(4)));
typedef uint32_t u32x4v __attribute__((ext_vector_type(4)));
typedef int i32x2 __attribute__((ext_vector_type(2)));

// SCALE * log2(e): folded into Q at the QKV epilogue.
#define C1 0.18033688011112042f

__device__ __forceinline__ u16 f2bf(float f) {             // RNE fp32 -> bf16
  union { float f; uint32_t u; } cv; cv.f = f;
  const uint32_t u = cv.u;
  return (u16)((u + 0x7fffu + ((u >> 16) & 1u)) >> 16);
}
__device__ __forceinline__ float ex2(float x) { return __builtin_amdgcn_exp2f(x); }

// packed fp32x2 -> bf16x2 (one instr, RNE; low half = first arg)
__device__ __forceinline__ uint32_t cvtpk_bf16(float lo, float hi) {
  uint32_t r;
  asm("v_cvt_pk_bf16_f32 %0, %1, %2" : "=v"(r) : "v"(lo), "v"(hi));
  return r;
}
// v_permlane32_swap_b32: swaps a's high 32 lanes with b's low 32 lanes.
__device__ __forceinline__ void pl32swap(uint32_t& a, uint32_t& b) {
  i32x2 r = __builtin_amdgcn_permlane32_swap((int)a, (int)b, false, false);
  a = (uint32_t)r.x; b = (uint32_t)r.y;
}
// async global->LDS, 16B per lane (GEMMs only -- attn reverted to reg-staging:
// R5 showed DMA has no register consumer, so its issue sinks toward the
// barrier and every __syncthreads eats exposed memory latency).
__device__ __forceinline__ void gload_lds16(const void* g, void* l) {
  __builtin_amdgcn_global_load_lds(
      (const __attribute__((address_space(1))) uint32_t*)g,
      (__attribute__((address_space(3))) uint32_t*)l, 16, 0, 0);
}

// ---------------- fp32 -> bf16 convert: all 3 arrays in ONE launch ----------------
__global__ __launch_bounds__(256) void cvt3_kernel(
    const float* __restrict__ a, u16* __restrict__ da, int na4,
    const float* __restrict__ b, u16* __restrict__ db, int nb4,
    const float* __restrict__ c, u16* __restrict__ dc, int nc4) {
  int i = blockIdx.x * 256 + threadIdx.x;
  const float* s; u16* d;
  if (i < na4)             { s = a; d = da; }
  else if (i < na4 + nb4)  { s = b; d = db; i -= na4; }
  else if (i < na4 + nb4 + nc4) { s = c; d = dc; i -= na4 + nb4; }
  else return;
  const float4 f = ((const float4*)s)[i];
  u16x4 r;
  r[0] = f2bf(f.x); r[1] = f2bf(f.y); r[2] = f2bf(f.z); r[3] = f2bf(f.w);
  ((u16x4*)d)[i] = r;
}

// ---------------- QKV GEMM: C[8192,2304] = x @ qkv_w^T + b, scattered epilogue ----
// m97-style staging (R4-verified): global_load_lds width=16 into linear
// [128][32]-u16 panels, both-sides chunk swizzle (rule #21).
__global__ __launch_bounds__(256) void gemm_qkv(const u16* __restrict__ A,
    const u16* __restrict__ B, const float* __restrict__ bias,
    u16* __restrict__ qg, u16* __restrict__ kg, u16* __restrict__ vtg) {
  __shared__ __align__(16) u16 at[128 * 32];
  __shared__ __align__(16) u16 bt[128 * 32];
  const int tid  = threadIdx.x;
  const int lane = tid & 63;
  const int w    = tid >> 6;
  const int quad = lane >> 4;
  const int col  = lane & 15;
  const int m0 = blockIdx.y * 128;
  const int n0 = blockIdx.x * 128;
  const int srow = tid >> 2;                         // 0..63
  const int schk = ((tid & 3) ^ (srow & 3)) * 8;     // swizzled source chunk
  const int wm = (w >> 1) * 64;
  const int wn = (w & 1) * 64;
  const int xq = (quad ^ (col & 3)) * 8;             // swizzled read slot

  const f4v fz = {0.f, 0.f, 0.f, 0.f};
  f4v acc[4][4];
#pragma unroll
  for (int i = 0; i < 4; i++)
#pragma unroll
    for (int j = 0; j < 4; j++) acc[i][j] = fz;

  const u16* ga0 = A + (size_t)(m0 + srow) * NDIM + schk;
  const u16* ga1 = A + (size_t)(m0 + 64 + srow) * NDIM + schk;
  const u16* gb0 = B + (size_t)(n0 + srow) * NDIM + schk;
  const u16* gb1 = B + (size_t)(n0 + 64 + srow) * NDIM + schk;
  u16* const la = at + (size_t)w * 512;
  u16* const lb = bt + (size_t)w * 512;

  for (int k0 = 0; k0 < NDIM; k0 += 32) {
    __syncthreads();                  // prior compute done reading LDS
    gload_lds16(ga0 + k0, la);
    gload_lds16(ga1 + k0, la + 2048);
    gload_lds16(gb0 + k0, lb);
    gload_lds16(gb1 + k0, lb + 2048);
    __syncthreads();                  // vmcnt drained -> tiles in LDS
    s8v af[4], bf[4];
#pragma unroll
    for (int i = 0; i < 4; i++)
      af[i] = *(const s8v*)(at + (wm + i * 16 + col) * 32 + xq);
#pragma unroll
    for (int j = 0; j < 4; j++)
      bf[j] = *(const s8v*)(bt + (wn + j * 16 + col) * 32 + xq);
#pragma unroll
    for (int i = 0; i < 4; i++)
#pragma unroll
      for (int j = 0; j < 4; j++)
        acc[i][j] = __builtin_amdgcn_mfma_f32_16x16x32_bf16(af[i], bf[j], acc[i][j], 0, 0, 0);
  }

  const int wmg = m0 + wm;
  const int wng = n0 + wn;
  const int s = n0 / NDIM;   // 0=q 1=k 2=v, block-uniform (768 = 6*128)
#pragma unroll
  for (int j = 0; j < 4; j++) {
    const int c = wng + j * 16 + col;
    const float bv = bias[c];
    const int r = c - s * NDIM;
    const int h = r >> 6;
    const int d = r & 63;
#pragma unroll
    for (int i = 0; i < 4; i++) {
      const int mb = wmg + i * 16 + quad * 4;   // 4 consecutive rows (regs)
      const int bb = mb >> 12;
      const int n  = mb & 4095;
      const size_t hb = (size_t)(bb * NH + h);
      const f4v v = acc[i][j];
      if (s == 2) {
        u16x4 pk;
#pragma unroll
        for (int rg = 0; rg < 4; rg++) pk[rg] = f2bf(v[rg] + bv);
        *(u16x4*)(vtg + (hb * HD + d) * SEQ + n) = pk;   // transposed store
      } else if (s == 0) {
#pragma unroll
        for (int rg = 0; rg < 4; rg++)
          qg[(hb * SEQ + (size_t)(n + rg)) * HD + d] = f2bf((v[rg] + bv) * C1);
      } else {
#pragma unroll
        for (int rg = 0; rg < 4; rg++)
          kg[(hb * SEQ + (size_t)(n + rg)) * HD + d] = f2bf(v[rg] + bv);
      }
    }
  }
}

// ---------------- flash attention: (q-half x key-half) split on R2 mechanics ----
// Wave w = (pair = w>>1: q rows pair*64..+64) x (kth = w&1: keys kth*32..+32).
// Each K-frag read feeds 2 QK MFMAs (qfA/qfB), each V-frag read feeds 2 PV
// MFMAs -> LDS frag reads/block-iter 64 -> 32 (R4's binding pipe at ~66%).
// Staging/layout = R2/R4-verified: PSTR=72 conflict-free panels, reg-staged
// double-buffer (register consumer pins global loads early -- the R5 DMA
// variant let them sink to the barrier: uniform 30% dilution of all pipes).
// One-time cross-wave merge of the two key-halves through smem at loop end
// (R5-verified). st zero-init hoisted via persistent zacc.
__global__ __launch_bounds__(256, 3) void attn_kernel(const u16* __restrict__ qg,
    const u16* __restrict__ kg, const u16* __restrict__ vtg, u16* __restrict__ og) {
  __shared__ __align__(16) u16 smem[2][2][64 * PSTR];  // [buf][0=K,1=V][64r x 72]
  __shared__ float lred[2][64];                        // [pair][q_local]

  const int tid  = threadIdx.x;
  const int lane = tid & 63;
  const int w    = tid >> 6;
  const int hi   = lane >> 5;
  const int c    = lane & 31;
  const int kth  = w & 1;            // key half: keys kth*32 .. +32
  const int pair = w >> 1;           // q half: rows pair*64 .. +64
  // XCD swizzle: bh = blk % 24 -> all q-tiles of one (b,h) on one XCD.
  const int blk = blockIdx.x;
  const int bh  = blk % NBH;
  const int q0  = (blk / NBH) * 128;
  const size_t gbase = (size_t)bh * (SEQ * HD);
  const int qw = pair * 64;

  // Q B-frags (loop-invariant): qfA = q rows qw+c, qfB = rows qw+32+c
  s8v qfA[4], qfB[4];
#pragma unroll
  for (int s = 0; s < 4; s++) {
    qfA[s] = *(const s8v*)(qg + gbase + (size_t)(q0 + qw + c) * HD + s * 16 + hi * 8);
    qfB[s] = *(const s8v*)(qg + gbase + (size_t)(q0 + qw + 32 + c) * HD + s * 16 + hi * 8);
  }

  f16x zacc;                         // persistent zero C-operand
#pragma unroll
  for (int e = 0; e < 16; e++) zacc[e] = 0.f;
  f16x o00 = zacc, o01 = zacc, o10 = zacc, o11 = zacc;  // o[qhalf][dhalf]
  float l0a = 0.f, l1a = 0.f, l2a = 0.f, l3a = 0.f;
  float l0b = 0.f, l1b = 0.f, l2b = 0.f, l3b = 0.f;

  // staging: 8 lanes per row (row=tid>>3, chunk=(tid&7)*8), 2 passes of 32 rows
  const int srow8 = tid >> 3;        // 0..31
  const int sch8  = (tid & 7) * 8;   // 0..56
  const u16* kp = kg  + gbase + (size_t)srow8 * HD  + sch8;
  const u16* vp = vtg + gbase + (size_t)srow8 * SEQ;

  // prologue: tile 0 -> regs -> buf0
  s8v kr0 = *(const s8v*)(kp);
  s8v kr1 = *(const s8v*)(kp + (size_t)32 * HD);
  s8v vr0 = *(const s8v*)(vp + sch8);
  s8v vr1 = *(const s8v*)(vp + (size_t)32 * SEQ + sch8);
  *(s8v*)(smem[0][0] + srow8 * PSTR + sch8) = kr0;
  *(s8v*)(smem[0][0] + (32 + srow8) * PSTR + sch8) = kr1;
  *(s8v*)(smem[0][1] + srow8 * PSTR + sch8) = vr0;
  *(s8v*)(smem[0][1] + (32 + srow8) * PSTR + sch8) = vr1;

  const int kbase = (kth * 32 + c) * PSTR + hi * 8;   // K frag row base
  const int vcol  = kth * 32 + hi * 8;                // V frag col base

  for (int kb = 0; kb < SEQ; kb += 64) {
    const int cur = (kb >> 6) & 1;
    const u16* kt_ = smem[cur][0];
    const u16* vt_ = smem[cur][1];
    __syncthreads();               // buf[cur] ready; prev reads of buf[cur^1] done

    // issue next-tile global loads; reg consumers pin them early
    if (kb + 64 < SEQ) {
      kr0 = *(const s8v*)(kp + (size_t)(kb + 64) * HD);
      kr1 = *(const s8v*)(kp + (size_t)(kb + 96) * HD);
      vr0 = *(const s8v*)(vp + kb + 64 + sch8);
      vr1 = *(const s8v*)(vp + (size_t)32 * SEQ + kb + 64 + sch8);
    }

    // QK: 4 K-frag reads feed 8 MFMAs (both q-halves)
    __builtin_amdgcn_s_setprio(1);
    f16x sA, sB;
    {
      const s8v kf0 = *(const s8v*)(kt_ + kbase);
      sA = __builtin_amdgcn_mfma_f32_32x32x16_bf16(kf0, qfA[0], zacc, 0, 0, 0);
      sB = __builtin_amdgcn_mfma_f32_32x32x16_bf16(kf0, qfB[0], zacc, 0, 0, 0);
      const s8v kf1 = *(const s8v*)(kt_ + kbase + 16);
      sA = __builtin_amdgcn_mfma_f32_32x32x16_bf16(kf1, qfA[1], sA, 0, 0, 0);
      sB = __builtin_amdgcn_mfma_f32_32x32x16_bf16(kf1, qfB[1], sB, 0, 0, 0);
      const s8v kf2 = *(const s8v*)(kt_ + kbase + 32);
      sA = __builtin_amdgcn_mfma_f32_32x32x16_bf16(kf2, qfA[2], sA, 0, 0, 0);
      sB = __builtin_amdgcn_mfma_f32_32x32x16_bf16(kf2, qfB[2], sB, 0, 0, 0);
      const s8v kf3 = *(const s8v*)(kt_ + kbase + 48);
      sA = __builtin_amdgcn_mfma_f32_32x32x16_bf16(kf3, qfA[3], sA, 0, 0, 0);
      sB = __builtin_amdgcn_mfma_f32_32x32x16_bf16(kf3, qfB[3], sB, 0, 0, 0);
    }
    __builtin_amdgcn_s_setprio(0);

    // SM(sA) -> pa00 (local key slice 0), pa01 (slice 1)
    s8v pa00, pa01, pa10, pa11;
    {
      float p[16];
#pragma unroll
      for (int e = 0; e < 16; e++) p[e] = ex2(sA[e]);
      l0a += p[0] + p[4] + p[8]  + p[12];
      l1a += p[1] + p[5] + p[9]  + p[13];
      l2a += p[2] + p[6] + p[10] + p[14];
      l3a += p[3] + p[7] + p[11] + p[15];
      uint32_t k0 = cvtpk_bf16(p[0],  p[1]);
      uint32_t k1 = cvtpk_bf16(p[2],  p[3]);
      uint32_t k2 = cvtpk_bf16(p[4],  p[5]);
      uint32_t k3 = cvtpk_bf16(p[6],  p[7]);
      uint32_t k4 = cvtpk_bf16(p[8],  p[9]);
      uint32_t k5 = cvtpk_bf16(p[10], p[11]);
      uint32_t k6 = cvtpk_bf16(p[12], p[13]);
      uint32_t k7 = cvtpk_bf16(p[14], p[15]);
      pl32swap(k0, k2); pl32swap(k1, k3);
      pl32swap(k4, k6); pl32swap(k5, k7);
      u32x4v wA = {k0, k1, k2, k3};
      u32x4v wB = {k4, k5, k6, k7};
      pa00 = __builtin_bit_cast(s8v, wA);
      pa01 = __builtin_bit_cast(s8v, wB);
    }

    // PV-A: 4 V-frag reads (held for PV-B), q-half A accumulate
    s8v vf0, vf1, vf2, vf3;
    __builtin_amdgcn_s_setprio(1);
    {
      vf0 = *(const s8v*)(vt_ + c * PSTR + vcol);             // d 0..31,  ks 0
      vf1 = *(const s8v*)(vt_ + (32 + c) * PSTR + vcol);      // d 32..63, ks 0
      vf2 = *(const s8v*)(vt_ + c * PSTR + vcol + 16);        // d 0..31,  ks 1
      vf3 = *(const s8v*)(vt_ + (32 + c) * PSTR + vcol + 16); // d 32..63, ks 1
      o00 = __builtin_amdgcn_mfma_f32_32x32x16_bf16(pa00, vf0, o00, 0, 0, 0);
      o01 = __builtin_amdgcn_mfma_f32_32x32x16_bf16(pa00, vf1, o01, 0, 0, 0);
      o00 = __builtin_amdgcn_mfma_f32_32x32x16_bf16(pa01, vf2, o00, 0, 0, 0);
      o01 = __builtin_amdgcn_mfma_f32_32x32x16_bf16(pa01, vf3, o01, 0, 0, 0);
    }
    __builtin_amdgcn_s_setprio(0);

    // SM(sB) -> pa10, pa11 (overlaps PV-A MFMAs)
    {
      float p[16];
#pragma unroll
      for (int e = 0; e < 16; e++) p[e] = ex2(sB[e]);
      l0b += p[0] + p[4] + p[8]  + p[12];
      l1b += p[1] + p[5] + p[9]  + p[13];
      l2b += p[2] + p[6] + p[10] + p[14];
      l3b += p[3] + p[7] + p[11] + p[15];
      uint32_t k0 = cvtpk_bf16(p[0],  p[1]);
      uint32_t k1 = cvtpk_bf16(p[2],  p[3]);
      uint32_t k2 = cvtpk_bf16(p[4],  p[5]);
      uint32_t k3 = cvtpk_bf16(p[6],  p[7]);
      uint32_t k4 = cvtpk_bf16(p[8],  p[9]);
      uint32_t k5 = cvtpk_bf16(p[10], p[11]);
      uint32_t k6 = cvtpk_bf16(p[12], p[13]);
      uint32_t k7 = cvtpk_bf16(p[14], p[15]);
      pl32swap(k0, k2); pl32swap(k1, k3);
      pl32swap(k4, k6); pl32swap(k5, k7);
      u32x4v wA = {k0, k1, k2, k3};
      u32x4v wB = {k4, k5, k6, k7};
      pa10 = __builtin_bit_cast(s8v, wA);
      pa11 = __builtin_bit_cast(s8v, wB);
    }

    // stage next tile: ds_write lgkm drains under PV-B below
    if (kb + 64 < SEQ) {
      u16* kn = (u16*)smem[cur ^ 1][0];
      u16* vn = (u16*)smem[cur ^ 1][1];
      *(s8v*)(kn + srow8 * PSTR + sch8) = kr0;
      *(s8v*)(kn + (32 + srow8) * PSTR + sch8) = kr1;
      *(s8v*)(vn + srow8 * PSTR + sch8) = vr0;
      *(s8v*)(vn + (32 + srow8) * PSTR + sch8) = vr1;
    }

    // PV-B: q-half B from held V-frags (zero extra LDS reads)
    __builtin_amdgcn_s_setprio(1);
    {
      o10 = __builtin_amdgcn_mfma_f32_32x32x16_bf16(pa10, vf0, o10, 0, 0, 0);
      o11 = __builtin_amdgcn_mfma_f32_32x32x16_bf16(pa10, vf1, o11, 0, 0, 0);
      o10 = __builtin_amdgcn_mfma_f32_32x32x16_bf16(pa11, vf2, o10, 0, 0, 0);
      o11 = __builtin_amdgcn_mfma_f32_32x32x16_bf16(pa11, vf3, o11, 0, 0, 0);
    }
    __builtin_amdgcn_s_setprio(0);
  }

  // ---- cross-wave merge (R5-verified): kth=1 ships O,l; kth=0 reduces+writes ----
  float* M  = (float*)smem + (size_t)pair * 4096;   // 64q x 64d f32 per pair
  float* LP = lred[pair];
  float ltA = l0a + l1a + l2a + l3a;  ltA += __shfl_xor(ltA, 32);
  float ltB = l0b + l1b + l2b + l3b;  ltB += __shfl_xor(ltB, 32);
  __syncthreads();                   // all K/V reads of smem done
  if (kth) {
    if (hi == 0) { LP[c] = ltA; LP[32 + c] = ltB; }
#pragma unroll
    for (int r = 0; r < 16; r++) {
      const int rq = (r & 3) + 8 * (r >> 2) + 4 * hi;
      M[rq * 64 + c]             = o00[r];
      M[rq * 64 + 32 + c]        = o01[r];
      M[(32 + rq) * 64 + c]      = o10[r];
      M[(32 + rq) * 64 + 32 + c] = o11[r];
    }
  }
  __syncthreads();
  if (!kth) {
    const float invA = 1.0f / (ltA + LP[c]);
    const float invB = 1.0f / (ltB + LP[32 + c]);
    if (hi == 0) { LP[c] = invA; LP[32 + c] = invB; }   // broadcast via LDS
    const int b = bh / NH;
    const int h = bh % NH;
    u16* obase = og + (size_t)(b * SEQ + q0 + pair * 64) * NDIM + h * HD;
#pragma unroll
    for (int r = 0; r < 16; r++) {
      const int rq = (r & 3) + 8 * (r >> 2) + 4 * hi;
      const float iA = LP[rq];
      const float iB = LP[32 + rq];
      u16* r0 = obase + (size_t)rq * NDIM;
      u16* r1 = obase + (size_t)(32 + rq) * NDIM;
      r0[c]      = f2bf((o00[r] + M[rq * 64 + c]) * iA);
      r0[32 + c] = f2bf((o01[r] + M[rq * 64 + 32 + c]) * iA);
      r1[c]      = f2bf((o10[r] + M[(32 + rq) * 64 + c]) * iB);
      r1[32 + c] = f2bf((o11[r] + M[(32 + rq) * 64 + 32 + c]) * iB);
    }
  }
}

// ---------------- proj GEMM: out[8192,768] = attn @ proj_w^T + b (fp32 out) ----
// Same global_load_lds staging as gemm_qkv (R4-verified).
__global__ __launch_bounds__(256) void gemm_proj(const u16* __restrict__ A,
    const u16* __restrict__ B, const float* __restrict__ bias, float* __restrict__ out) {
  __shared__ __align__(16) u16 at[128 * 32];
  __shared__ __align__(16) u16 bt[128 * 32];
  const int tid  = threadIdx.x;
  const int lane = tid & 63;
  const int w    = tid >> 6;
  const int quad = lane >> 4;
  const int col  = lane & 15;
  const int m0 = blockIdx.y * 128;
  const int n0 = blockIdx.x * 128;
  const int srow = tid >> 2;
  const int schk = ((tid & 3) ^ (srow & 3)) * 8;
  const int wm = (w >> 1) * 64;
  const int wn = (w & 1) * 64;
  const int xq = (quad ^ (col & 3)) * 8;

  const f4v fz = {0.f, 0.f, 0.f, 0.f};
  f4v acc[4][4];
#pragma unroll
  for (int i = 0; i < 4; i++)
#pragma unroll
    for (int j = 0; j < 4; j++) acc[i][j] = fz;

  const u16* ga0 = A + (size_t)(m0 + srow) * NDIM + schk;
  const u16* ga1 = A + (size_t)(m0 + 64 + srow) * NDIM + schk;
  const u16* gb0 = B + (size_t)(n0 + srow) * NDIM + schk;
  const u16* gb1 = B + (size_t)(n0 + 64 + srow) * NDIM + schk;
  u16* const la = at + (size_t)w * 512;
  u16* const lb = bt + (size_t)w * 512;

  for (int k0 = 0; k0 < NDIM; k0 += 32) {
    __syncthreads();
    gload_lds16(ga0 + k0, la);
    gload_lds16(ga1 + k0, la + 2048);
    gload_lds16(gb0 + k0, lb);
    gload_lds16(gb1 + k0, lb + 2048);
    __syncthreads();
    s8v af[4], bf[4];
#pragma unroll
    for (int i = 0; i < 4; i++)
      af[i] = *(const s8v*)(at + (wm + i * 16 + col) * 32 + xq);
#pragma unroll
    for (int j = 0; j < 4; j++)
      bf[j] = *(const s8v*)(bt + (wn + j * 16 + col) * 32 + xq);
#pragma unroll
    for (int i = 0; i < 4; i++)
#pragma unroll
      for (int j = 0; j < 4; j++)
        acc[i][j] = __builtin_amdgcn_mfma_f32_16x16x32_bf16(af[i], bf[j], acc[i][j], 0, 0, 0);
  }

  const int wmg = m0 + wm;
  const int wng = n0 + wn;
#pragma unroll
  for (int j = 0; j < 4; j++) {
    const int c = wng + j * 16 + col;
    const float bv = bias[c];
#pragma unroll
    for (int i = 0; i < 4; i++) {
#pragma unroll
      for (int rg = 0; rg < 4; rg++)
        out[(size_t)(wmg + i * 16 + quad * 4 + rg) * NDIM + c] = acc[i][j][rg] + bv;
    }
  }
}

// ---------------- launch ----------------
extern "C" void kernel_launch(void* const* d_in, const int* in_sizes, int n_in,
                              void* d_out, int out_size, void* d_ws, size_t ws_size,
                              hipStream_t stream) {
  const float* x      = (const float*)d_in[0];
  const float* qkv_w  = (const float*)d_in[1];
  const float* qkv_b  = (const float*)d_in[2];
  const float* proj_w = (const float*)d_in[3];
  const float* proj_b = (const float*)d_in[4];
  float* out = (float*)d_out;

  u16* ws   = (u16*)d_ws;
  u16* x_bf = ws;                              // 8192*768
  u16* wq   = x_bf + (size_t)MTOT * NDIM;      // 2304*768
  u16* wp   = wq + (size_t)3 * NDIM * NDIM;    // 768*768
  u16* q_bf = wp + (size_t)NDIM * NDIM;        // 24*4096*64 each
  u16* k_bf = q_bf + (size_t)NBH * SEQ * HD;
  u16* vt   = k_bf + (size_t)NBH * SEQ * HD;
  u16* a_bf = vt + (size_t)NBH * SEQ * HD;     // 8192*768

  const int nx = MTOT * NDIM / 4, nw1 = 3 * NDIM * NDIM / 4, nw2 = NDIM * NDIM / 4;
  const int ntot = nx + nw1 + nw2;
  cvt3_kernel<<<(ntot + 255) / 256, 256, 0, stream>>>(x, x_bf, nx, qkv_w, wq, nw1,
                                                      proj_w, wp, nw2);

  gemm_qkv<<<dim3(18, 64), 256, 0, stream>>>(x_bf, wq, qkv_b, q_bf, k_bf, vt);
  attn_kernel<<<768, 256, 0, stream>>>(q_bf, k_bf, vt, a_bf);
  gemm_proj<<<dim3(6, 64), 256, 0, stream>>>(a_bf, wp, proj_b, out);
}

// Round 7
// 271.766 us; speedup vs baseline: 1.4036x; 1.4036x over previous
//
#include <hip/hip_runtime.h>
#include <stdint.h>

#define SEQ   4096
#define NDIM  768
#define HD    64
#define NH    12
#define NBH   24        // 2 * 12
#define MTOT  8192      // 2 * 4096

// Attention K/V panel row stride in u16: 64 elems + 8 pad. Word stride
// 36 ≡ 4 (mod 32): 8-lane read phases full-cover the 32 banks -> conflict-free
// (R2/R4-verified, 0 SQ_LDS_BANK_CONFLICT).
#define PSTR 72

typedef short s8v __attribute__((ext_vector_type(8)));     // 8 bf16 (as shorts), 16B
typedef float f4v __attribute__((ext_vector_type(4)));
typedef float f16x __attribute__((ext_vector_type(16)));
typedef unsigned short u16;
typedef u16 u16x4 __attribute__((ext_vector_type(4)));
typedef uint32_t u32x4v __attribute__((ext_vector_type(4)));
typedef int i32x2 __attribute__((ext_vector_type(2)));

// SCALE * log2(e): folded into Q at the QKV epilogue.
#define C1 0.18033688011112042f

__device__ __forceinline__ u16 f2bf(float f) {             // RNE fp32 -> bf16
  union { float f; uint32_t u; } cv; cv.f = f;
  const uint32_t u = cv.u;
  return (u16)((u + 0x7fffu + ((u >> 16) & 1u)) >> 16);
}
__device__ __forceinline__ float ex2(float x) { return __builtin_amdgcn_exp2f(x); }

// packed fp32x2 -> bf16x2 (one instr, RNE; low half = first arg)
__device__ __forceinline__ uint32_t cvtpk_bf16(float lo, float hi) {
  uint32_t r;
  asm("v_cvt_pk_bf16_f32 %0, %1, %2" : "=v"(r) : "v"(lo), "v"(hi));
  return r;
}
// v_permlane32_swap_b32: swaps a's high 32 lanes with b's low 32 lanes.
__device__ __forceinline__ void pl32swap(uint32_t& a, uint32_t& b) {
  i32x2 r = __builtin_amdgcn_permlane32_swap((int)a, (int)b, false, false);
  a = (uint32_t)r.x; b = (uint32_t)r.y;
}
// async global->LDS, 16B per lane (GEMMs only; R5 showed attn must reg-stage).
__device__ __forceinline__ void gload_lds16(const void* g, void* l) {
  __builtin_amdgcn_global_load_lds(
      (const __attribute__((address_space(1))) uint32_t*)g,
      (__attribute__((address_space(3))) uint32_t*)l, 16, 0, 0);
}

// ---------------- fp32 -> bf16 convert: all 3 arrays in ONE launch ----------------
__global__ __launch_bounds__(256) void cvt3_kernel(
    const float* __restrict__ a, u16* __restrict__ da, int na4,
    const float* __restrict__ b, u16* __restrict__ db, int nb4,
    const float* __restrict__ c, u16* __restrict__ dc, int nc4) {
  int i = blockIdx.x * 256 + threadIdx.x;
  const float* s; u16* d;
  if (i < na4)             { s = a; d = da; }
  else if (i < na4 + nb4)  { s = b; d = db; i -= na4; }
  else if (i < na4 + nb4 + nc4) { s = c; d = dc; i -= na4 + nb4; }
  else return;
  const float4 f = ((const float4*)s)[i];
  u16x4 r;
  r[0] = f2bf(f.x); r[1] = f2bf(f.y); r[2] = f2bf(f.z); r[3] = f2bf(f.w);
  ((u16x4*)d)[i] = r;
}

// ---------------- QKV GEMM: C[8192,2304] = x @ qkv_w^T + b, scattered epilogue ----
// R4-verified global_load_lds staging. New this round:
// (1) q stored TRANSPOSED [bh][d][n] like v -> u16x4 epilogue stores (was 64
//     scalar u16 stores/thread, poorly coalesced); attn loads Q scalar, once
//     per block (amortized over 64 iters).
// (2) bijective XCD swizzle (1152 % 8 == 0): each XCD owns an 8-m-row band,
//     n fastest -> A band (1.6MB) L2-resident per XCD, B (3.5MB) shared.
__global__ __launch_bounds__(256) void gemm_qkv(const u16* __restrict__ A,
    const u16* __restrict__ B, const float* __restrict__ bias,
    u16* __restrict__ qtg, u16* __restrict__ kg, u16* __restrict__ vtg) {
  __shared__ __align__(16) u16 at[128 * 32];
  __shared__ __align__(16) u16 bt[128 * 32];
  const int tid  = threadIdx.x;
  const int lane = tid & 63;
  const int w    = tid >> 6;
  const int quad = lane >> 4;
  const int col  = lane & 15;
  const int bid  = blockIdx.x;                       // 1152 blocks
  const int wgid = (bid & 7) * 144 + (bid >> 3);     // XCD-chunked, bijective
  const int n0 = (wgid % 18) * 128;
  const int m0 = (wgid / 18) * 128;
  const int srow = tid >> 2;                         // 0..63
  const int schk = ((tid & 3) ^ (srow & 3)) * 8;     // swizzled source chunk
  const int wm = (w >> 1) * 64;
  const int wn = (w & 1) * 64;
  const int xq = (quad ^ (col & 3)) * 8;             // swizzled read slot

  const f4v fz = {0.f, 0.f, 0.f, 0.f};
  f4v acc[4][4];
#pragma unroll
  for (int i = 0; i < 4; i++)
#pragma unroll
    for (int j = 0; j < 4; j++) acc[i][j] = fz;

  const u16* ga0 = A + (size_t)(m0 + srow) * NDIM + schk;
  const u16* ga1 = A + (size_t)(m0 + 64 + srow) * NDIM + schk;
  const u16* gb0 = B + (size_t)(n0 + srow) * NDIM + schk;
  const u16* gb1 = B + (size_t)(n0 + 64 + srow) * NDIM + schk;
  u16* const la = at + (size_t)w * 512;
  u16* const lb = bt + (size_t)w * 512;

  for (int k0 = 0; k0 < NDIM; k0 += 32) {
    __syncthreads();                  // prior compute done reading LDS
    gload_lds16(ga0 + k0, la);
    gload_lds16(ga1 + k0, la + 2048);
    gload_lds16(gb0 + k0, lb);
    gload_lds16(gb1 + k0, lb + 2048);
    __syncthreads();                  // vmcnt drained -> tiles in LDS
    s8v af[4], bf[4];
#pragma unroll
    for (int i = 0; i < 4; i++)
      af[i] = *(const s8v*)(at + (wm + i * 16 + col) * 32 + xq);
#pragma unroll
    for (int j = 0; j < 4; j++)
      bf[j] = *(const s8v*)(bt + (wn + j * 16 + col) * 32 + xq);
#pragma unroll
    for (int i = 0; i < 4; i++)
#pragma unroll
      for (int j = 0; j < 4; j++)
        acc[i][j] = __builtin_amdgcn_mfma_f32_16x16x32_bf16(af[i], bf[j], acc[i][j], 0, 0, 0);
  }

  const int wmg = m0 + wm;
  const int wng = n0 + wn;
  const int s = n0 / NDIM;   // 0=q 1=k 2=v, block-uniform (768 = 6*128)
#pragma unroll
  for (int j = 0; j < 4; j++) {
    const int c = wng + j * 16 + col;
    const float bv = bias[c];
    const int r = c - s * NDIM;
    const int h = r >> 6;
    const int d = r & 63;
#pragma unroll
    for (int i = 0; i < 4; i++) {
      const int mb = wmg + i * 16 + quad * 4;   // 4 consecutive rows (regs)
      const int bb = mb >> 12;
      const int n  = mb & 4095;
      const size_t hb = (size_t)(bb * NH + h);
      const f4v v = acc[i][j];
      if (s == 2) {
        u16x4 pk;
#pragma unroll
        for (int rg = 0; rg < 4; rg++) pk[rg] = f2bf(v[rg] + bv);
        *(u16x4*)(vtg + (hb * HD + d) * SEQ + n) = pk;   // transposed store
      } else if (s == 0) {
        u16x4 pk;                                        // q transposed too
#pragma unroll
        for (int rg = 0; rg < 4; rg++) pk[rg] = f2bf((v[rg] + bv) * C1);
        *(u16x4*)(qtg + (hb * HD + d) * SEQ + n) = pk;
      } else {
#pragma unroll
        for (int rg = 0; rg < 4; rg++)
          kg[(hb * SEQ + (size_t)(n + rg)) * HD + d] = f2bf(v[rg] + bv);
      }
    }
  }
}

// ---------------- flash attention, 32x32 MFMA + in-register P (T12) ----------------
// R2/R4-verified structure (116.6us, 883 TF): K/V LDS double-buffered PSTR=72
// panels, reg-staged (register consumers pin global loads early), one
// barrier/iter, split-tile interleave QK -> SM(st0) -> PV(ks0,1) -> SM(st1)
// -> stage -> PV(ks2,3), setprio on MFMA clusters. Q now read from the
// TRANSPOSED [bh][d][n] layout (scalar gathers, once per block).
__global__ __launch_bounds__(256, 3) void attn_kernel(const u16* __restrict__ qtg,
    const u16* __restrict__ kg, const u16* __restrict__ vtg, u16* __restrict__ og) {
  __shared__ __align__(16) u16 kls[2][64 * PSTR];   // [buf][key][64 d + 8 pad]
  __shared__ __align__(16) u16 vls[2][64 * PSTR];   // [buf][d row][64 keys + 8 pad]
  __shared__ float lws[4][32];                      // per-wave 1/l broadcast

  const int tid  = threadIdx.x;
  const int lane = tid & 63;
  const int w    = tid >> 6;
  const int hi   = lane >> 5;
  const int c    = lane & 31;
  // XCD swizzle: bh = blk % 24 -> all q-tiles of one (b,h) on one XCD.
  const int blk = blockIdx.x;
  const int bh  = blk % NBH;
  const int q0  = (blk / NBH) * 128;
  const size_t gbase = (size_t)bh * (SEQ * HD);
  const int wq = w * 32;           // this wave's 32 q rows

  // Q B-frags from transposed layout: qf[s][j] = Q[d=s*16+hi*8+j][q=q0+wq+c]
  s8v qf[4];
  {
    const u16* qp = qtg + gbase + (q0 + wq + c);
#pragma unroll
    for (int s = 0; s < 4; s++) {
      s8v t;
#pragma unroll
      for (int j = 0; j < 8; j++)
        t[j] = (short)qp[(size_t)(s * 16 + hi * 8 + j) * SEQ];
      qf[s] = t;
    }
  }

  f16x o0, o1;                     // O[q=32][d=0..31], O[q][d=32..63]
#pragma unroll
  for (int e = 0; e < 16; e++) { o0[e] = 0.f; o1[e] = 0.f; }
  float l0 = 0.f, l1 = 0.f, l2 = 0.f, l3 = 0.f;

  // staging: 8 lanes per row (row=tid>>3, chunk=(tid&7)*8), 2 passes of 32 rows
  const int srow8 = tid >> 3;        // 0..31
  const int sch8  = (tid & 7) * 8;   // 0..56
  const u16* kp = kg  + gbase + (size_t)srow8 * HD  + sch8;   // +(kb+32p)*HD
  const u16* vp = vtg + gbase + (size_t)srow8 * SEQ;          // +32p*SEQ +kb+sch8

  // prologue: tile 0 -> regs -> buf0
  s8v kr0 = *(const s8v*)(kp);
  s8v kr1 = *(const s8v*)(kp + (size_t)32 * HD);
  s8v vr0 = *(const s8v*)(vp + sch8);
  s8v vr1 = *(const s8v*)(vp + (size_t)32 * SEQ + sch8);
  *(s8v*)(kls[0] + srow8 * PSTR + sch8) = kr0;
  *(s8v*)(kls[0] + (32 + srow8) * PSTR + sch8) = kr1;
  *(s8v*)(vls[0] + srow8 * PSTR + sch8) = vr0;
  *(s8v*)(vls[0] + (32 + srow8) * PSTR + sch8) = vr1;

  for (int kb = 0; kb < SEQ; kb += 64) {
    const int cur = (kb >> 6) & 1;
    const u16* kt_ = kls[cur];
    const u16* vt_ = vls[cur];
    __syncthreads();               // buf[cur] ready; prev reads of buf[cur^1] done

    // issue next-tile global loads; in flight under the whole compute phase
    if (kb + 64 < SEQ) {
      kr0 = *(const s8v*)(kp + (size_t)(kb + 64) * HD);
      kr1 = *(const s8v*)(kp + (size_t)(kb + 96) * HD);
      vr0 = *(const s8v*)(vp + kb + 64 + sch8);
      vr1 = *(const s8v*)(vp + (size_t)32 * SEQ + kb + 64 + sch8);
    }

    // St = K @ Q^T: st0 = keys 0..31, st1 = keys 32..63 (rows), q = cols
    f16x st0, st1;
#pragma unroll
    for (int e = 0; e < 16; e++) { st0[e] = 0.f; st1[e] = 0.f; }
    __builtin_amdgcn_s_setprio(1);
#pragma unroll
    for (int s = 0; s < 4; s++) {
      const s8v k0 = *(const s8v*)(kt_ + c * PSTR + s * 16 + hi * 8);
      const s8v k1 = *(const s8v*)(kt_ + (32 + c) * PSTR + s * 16 + hi * 8);
      st0 = __builtin_amdgcn_mfma_f32_32x32x16_bf16(k0, qf[s], st0, 0, 0, 0);
      st1 = __builtin_amdgcn_mfma_f32_32x32x16_bf16(k1, qf[s], st1, 0, 0, 0);
    }
    __builtin_amdgcn_s_setprio(0);

    // SM(st0): exp2 -> cvt_pk bf16 -> hi-half exchange -> PV A-frags pa0,pa1
    s8v pa0, pa1, pa2, pa3;
    {
      float p[16];
#pragma unroll
      for (int e = 0; e < 16; e++) p[e] = ex2(st0[e]);
      l0 += p[0] + p[4] + p[8]  + p[12];
      l1 += p[1] + p[5] + p[9]  + p[13];
      l2 += p[2] + p[6] + p[10] + p[14];
      l3 += p[3] + p[7] + p[11] + p[15];
      uint32_t k0 = cvtpk_bf16(p[0],  p[1]);
      uint32_t k1 = cvtpk_bf16(p[2],  p[3]);
      uint32_t k2 = cvtpk_bf16(p[4],  p[5]);
      uint32_t k3 = cvtpk_bf16(p[6],  p[7]);
      uint32_t k4 = cvtpk_bf16(p[8],  p[9]);
      uint32_t k5 = cvtpk_bf16(p[10], p[11]);
      uint32_t k6 = cvtpk_bf16(p[12], p[13]);
      uint32_t k7 = cvtpk_bf16(p[14], p[15]);
      pl32swap(k0, k2); pl32swap(k1, k3);   // -> slots 0..3 of ks=0
      pl32swap(k4, k6); pl32swap(k5, k7);   // -> slots 0..3 of ks=1
      u32x4v wA = {k0, k1, k2, k3};
      u32x4v wB = {k4, k5, k6, k7};
      pa0 = __builtin_bit_cast(s8v, wA);
      pa1 = __builtin_bit_cast(s8v, wB);
    }

    // PV ks=0,1 (keys 0..31) — overlaps SM(st1) below
    __builtin_amdgcn_s_setprio(1);
    {
      const s8v v00 = *(const s8v*)(vt_ + c * PSTR + hi * 8);
      const s8v v01 = *(const s8v*)(vt_ + (32 + c) * PSTR + hi * 8);
      const s8v v10 = *(const s8v*)(vt_ + c * PSTR + 16 + hi * 8);
      const s8v v11 = *(const s8v*)(vt_ + (32 + c) * PSTR + 16 + hi * 8);
      o0 = __builtin_amdgcn_mfma_f32_32x32x16_bf16(pa0, v00, o0, 0, 0, 0);
      o1 = __builtin_amdgcn_mfma_f32_32x32x16_bf16(pa0, v01, o1, 0, 0, 0);
      o0 = __builtin_amdgcn_mfma_f32_32x32x16_bf16(pa1, v10, o0, 0, 0, 0);
      o1 = __builtin_amdgcn_mfma_f32_32x32x16_bf16(pa1, v11, o1, 0, 0, 0);
    }
    __builtin_amdgcn_s_setprio(0);

    // SM(st1) -> pa2,pa3 (VALU/TRANS, overlaps PV cluster above)
    {
      float p[16];
#pragma unroll
      for (int e = 0; e < 16; e++) p[e] = ex2(st1[e]);
      l0 += p[0] + p[4] + p[8]  + p[12];
      l1 += p[1] + p[5] + p[9]  + p[13];
      l2 += p[2] + p[6] + p[10] + p[14];
      l3 += p[3] + p[7] + p[11] + p[15];
      uint32_t k0 = cvtpk_bf16(p[0],  p[1]);
      uint32_t k1 = cvtpk_bf16(p[2],  p[3]);
      uint32_t k2 = cvtpk_bf16(p[4],  p[5]);
      uint32_t k3 = cvtpk_bf16(p[6],  p[7]);
      uint32_t k4 = cvtpk_bf16(p[8],  p[9]);
      uint32_t k5 = cvtpk_bf16(p[10], p[11]);
      uint32_t k6 = cvtpk_bf16(p[12], p[13]);
      uint32_t k7 = cvtpk_bf16(p[14], p[15]);
      pl32swap(k0, k2); pl32swap(k1, k3);
      pl32swap(k4, k6); pl32swap(k5, k7);
      u32x4v wA = {k0, k1, k2, k3};
      u32x4v wB = {k4, k5, k6, k7};
      pa2 = __builtin_bit_cast(s8v, wA);
      pa3 = __builtin_bit_cast(s8v, wB);
    }

    // stage next tile NOW: ds_write lgkm drains under the PV cluster below.
    if (kb + 64 < SEQ) {
      u16* kn = (u16*)kls[cur ^ 1];
      u16* vn = (u16*)vls[cur ^ 1];
      *(s8v*)(kn + srow8 * PSTR + sch8) = kr0;
      *(s8v*)(kn + (32 + srow8) * PSTR + sch8) = kr1;
      *(s8v*)(vn + srow8 * PSTR + sch8) = vr0;
      *(s8v*)(vn + (32 + srow8) * PSTR + sch8) = vr1;
    }

    // PV ks=2,3 (keys 32..63)
    __builtin_amdgcn_s_setprio(1);
    {
      const s8v v20 = *(const s8v*)(vt_ + c * PSTR + 32 + hi * 8);
      const s8v v21 = *(const s8v*)(vt_ + (32 + c) * PSTR + 32 + hi * 8);
      const s8v v30 = *(const s8v*)(vt_ + c * PSTR + 48 + hi * 8);
      const s8v v31 = *(const s8v*)(vt_ + (32 + c) * PSTR + 48 + hi * 8);
      o0 = __builtin_amdgcn_mfma_f32_32x32x16_bf16(pa2, v20, o0, 0, 0, 0);
      o1 = __builtin_amdgcn_mfma_f32_32x32x16_bf16(pa2, v21, o1, 0, 0, 0);
      o0 = __builtin_amdgcn_mfma_f32_32x32x16_bf16(pa3, v30, o0, 0, 0, 0);
      o1 = __builtin_amdgcn_mfma_f32_32x32x16_bf16(pa3, v31, o1, 0, 0, 0);
    }
    __builtin_amdgcn_s_setprio(0);
  }

  // epilogue: l[q=c] lives column-indexed; O rows are q -> broadcast 1/l via
  // tiny per-wave LDS (wave-private region, broadcast reads)
  float lt = l0 + l1 + l2 + l3;
  lt += __shfl_xor(lt, 32);
  const float inv = 1.0f / lt;
  if (hi == 0) lws[w][c] = inv;

  const int b = bh / NH;
  const int h = bh % NH;
  u16* obase = og + (size_t)(b * SEQ + q0 + wq) * NDIM + h * HD + c;
#pragma unroll
  for (int r = 0; r < 16; r++) {
    const int row = (r & 3) + 8 * (r >> 2) + 4 * hi;   // q offset in wave tile
    const float invr = lws[w][row];                     // broadcast read
    u16* rp = obase + (size_t)row * NDIM;
    rp[0]  = f2bf(o0[r] * invr);
    rp[32] = f2bf(o1[r] * invr);
  }
}

// ---------------- proj GEMM: out[8192,768] = attn @ proj_w^T + b (fp32 out) ----
// R4 staging + bijective XCD swizzle (384 % 8 == 0, 8-m-row band per XCD).
__global__ __launch_bounds__(256) void gemm_proj(const u16* __restrict__ A,
    const u16* __restrict__ B, const float* __restrict__ bias, float* __restrict__ out) {
  __shared__ __align__(16) u16 at[128 * 32];
  __shared__ __align__(16) u16 bt[128 * 32];
  const int tid  = threadIdx.x;
  const int lane = tid & 63;
  const int w    = tid >> 6;
  const int quad = lane >> 4;
  const int col  = lane & 15;
  const int bid  = blockIdx.x;                       // 384 blocks
  const int wgid = (bid & 7) * 48 + (bid >> 3);
  const int n0 = (wgid % 6) * 128;
  const int m0 = (wgid / 6) * 128;
  const int srow = tid >> 2;
  const int schk = ((tid & 3) ^ (srow & 3)) * 8;
  const int wm = (w >> 1) * 64;
  const int wn = (w & 1) * 64;
  const int xq = (quad ^ (col & 3)) * 8;

  const f4v fz = {0.f, 0.f, 0.f, 0.f};
  f4v acc[4][4];
#pragma unroll
  for (int i = 0; i < 4; i++)
#pragma unroll
    for (int j = 0; j < 4; j++) acc[i][j] = fz;

  const u16* ga0 = A + (size_t)(m0 + srow) * NDIM + schk;
  const u16* ga1 = A + (size_t)(m0 + 64 + srow) * NDIM + schk;
  const u16* gb0 = B + (size_t)(n0 + srow) * NDIM + schk;
  const u16* gb1 = B + (size_t)(n0 + 64 + srow) * NDIM + schk;
  u16* const la = at + (size_t)w * 512;
  u16* const lb = bt + (size_t)w * 512;

  for (int k0 = 0; k0 < NDIM; k0 += 32) {
    __syncthreads();
    gload_lds16(ga0 + k0, la);
    gload_lds16(ga1 + k0, la + 2048);
    gload_lds16(gb0 + k0, lb);
    gload_lds16(gb1 + k0, lb + 2048);
    __syncthreads();
    s8v af[4], bf[4];
#pragma unroll
    for (int i = 0; i < 4; i++)
      af[i] = *(const s8v*)(at + (wm + i * 16 + col) * 32 + xq);
#pragma unroll
    for (int j = 0; j < 4; j++)
      bf[j] = *(const s8v*)(bt + (wn + j * 16 + col) * 32 + xq);
#pragma unroll
    for (int i = 0; i < 4; i++)
#pragma unroll
      for (int j = 0; j < 4; j++)
        acc[i][j] = __builtin_amdgcn_mfma_f32_16x16x32_bf16(af[i], bf[j], acc[i][j], 0, 0, 0);
  }

  const int wmg = m0 + wm;
  const int wng = n0 + wn;
#pragma unroll
  for (int j = 0; j < 4; j++) {
    const int c = wng + j * 16 + col;
    const float bv = bias[c];
#pragma unroll
    for (int i = 0; i < 4; i++) {
#pragma unroll
      for (int rg = 0; rg < 4; rg++)
        out[(size_t)(wmg + i * 16 + quad * 4 + rg) * NDIM + c] = acc[i][j][rg] + bv;
    }
  }
}

// ---------------- launch ----------------
extern "C" void kernel_launch(void* const* d_in, const int* in_sizes, int n_in,
                              void* d_out, int out_size, void* d_ws, size_t ws_size,
                              hipStream_t stream) {
  const float* x      = (const float*)d_in[0];
  const float* qkv_w  = (const float*)d_in[1];
  const float* qkv_b  = (const float*)d_in[2];
  const float* proj_w = (const float*)d_in[3];
  const float* proj_b = (const float*)d_in[4];
  float* out = (float*)d_out;

  u16* ws   = (u16*)d_ws;
  u16* x_bf = ws;                              // 8192*768
  u16* wq   = x_bf + (size_t)MTOT * NDIM;      // 2304*768
  u16* wp   = wq + (size_t)3 * NDIM * NDIM;    // 768*768
  u16* qt   = wp + (size_t)NDIM * NDIM;        // 24*64*4096 (transposed q)
  u16* k_bf = qt + (size_t)NBH * SEQ * HD;
  u16* vt   = k_bf + (size_t)NBH * SEQ * HD;
  u16* a_bf = vt + (size_t)NBH * SEQ * HD;     // 8192*768

  const int nx = MTOT * NDIM / 4, nw1 = 3 * NDIM * NDIM / 4, nw2 = NDIM * NDIM / 4;
  const int ntot = nx + nw1 + nw2;
  cvt3_kernel<<<(ntot + 255) / 256, 256, 0, stream>>>(x, x_bf, nx, qkv_w, wq, nw1,
                                                      proj_w, wp, nw2);

  gemm_qkv<<<1152, 256, 0, stream>>>(x_bf, wq, qkv_b, qt, k_bf, vt);
  attn_kernel<<<768, 256, 0, stream>>>(qt, k_bf, vt, a_bf);
  gemm_proj<<<384, 256, 0, stream>>>(a_bf, wp, proj_b, out);
}

// Round 8
// 261.148 us; speedup vs baseline: 1.4606x; 1.0407x over previous
//
#include <hip/hip_runtime.h>
#include <stdint.h>

#define SEQ   4096
#define NDIM  768
#define HD    64
#define NH    12
#define NBH   24        // 2 * 12
#define MTOT  8192      // 2 * 4096

// Attention K/V panel row stride in u16: 64 elems + 8 pad. Word stride
// 36 ≡ 4 (mod 32): 8-lane read phases full-cover the 32 banks -> conflict-free
// (R2/R4-verified, 0 SQ_LDS_BANK_CONFLICT).
#define PSTR 72

typedef short s8v __attribute__((ext_vector_type(8)));     // 8 bf16 (as shorts), 16B
typedef float f4v __attribute__((ext_vector_type(4)));
typedef float f16x __attribute__((ext_vector_type(16)));
typedef unsigned short u16;
typedef u16 u16x4 __attribute__((ext_vector_type(4)));
typedef uint32_t u32x4v __attribute__((ext_vector_type(4)));
typedef int i32x2 __attribute__((ext_vector_type(2)));

// SCALE * log2(e): folded into Q at the QKV epilogue.
#define C1 0.18033688011112042f

__device__ __forceinline__ u16 f2bf(float f) {             // RNE fp32 -> bf16
  union { float f; uint32_t u; } cv; cv.f = f;
  const uint32_t u = cv.u;
  return (u16)((u + 0x7fffu + ((u >> 16) & 1u)) >> 16);
}
__device__ __forceinline__ float ex2(float x) { return __builtin_amdgcn_exp2f(x); }

// packed fp32x2 -> bf16x2 (one instr, RNE; low half = first arg)
__device__ __forceinline__ uint32_t cvtpk_bf16(float lo, float hi) {
  uint32_t r;
  asm("v_cvt_pk_bf16_f32 %0, %1, %2" : "=v"(r) : "v"(lo), "v"(hi));
  return r;
}
// v_permlane32_swap_b32: swaps a's high 32 lanes with b's low 32 lanes.
__device__ __forceinline__ void pl32swap(uint32_t& a, uint32_t& b) {
  i32x2 r = __builtin_amdgcn_permlane32_swap((int)a, (int)b, false, false);
  a = (uint32_t)r.x; b = (uint32_t)r.y;
}
// async global->LDS, 16B per lane (GEMMs only; R5 showed attn must reg-stage).
__device__ __forceinline__ void gload_lds16(const void* g, void* l) {
  __builtin_amdgcn_global_load_lds(
      (const __attribute__((address_space(1))) uint32_t*)g,
      (__attribute__((address_space(3))) uint32_t*)l, 16, 0, 0);
}

// ---------------- fp32 -> bf16 convert: all 3 arrays in ONE launch ----------------
__global__ __launch_bounds__(256) void cvt3_kernel(
    const float* __restrict__ a, u16* __restrict__ da, int na4,
    const float* __restrict__ b, u16* __restrict__ db, int nb4,
    const float* __restrict__ c, u16* __restrict__ dc, int nc4) {
  int i = blockIdx.x * 256 + threadIdx.x;
  const float* s; u16* d;
  if (i < na4)             { s = a; d = da; }
  else if (i < na4 + nb4)  { s = b; d = db; i -= na4; }
  else if (i < na4 + nb4 + nc4) { s = c; d = dc; i -= na4 + nb4; }
  else return;
  const float4 f = ((const float4*)s)[i];
  u16x4 r;
  r[0] = f2bf(f.x); r[1] = f2bf(f.y); r[2] = f2bf(f.z); r[3] = f2bf(f.w);
  ((u16x4*)d)[i] = r;
}

// ---------------- QKV GEMM: C[8192,2304] = x @ qkv_w^T + b, scattered epilogue ----
// BK=64 this round: 12 barrier-pairs instead of 24 (short-K amortization --
// K=768 is the regime where per-step barrier drains dominate, cf. m102 shape
// curve). Staging: 8 gload_lds16 into linear [128][64]-u16 panels (16KB each);
// both-sides XOR swizzle chunk ^= row&7 (source chunk pre-swizzled, read slot
// xo = ((kk*4+quad) ^ (col&7)); row&7 == col&7 since wm,i*16 are 0 mod 8).
// Read phase: 8 phys chunks x 4 words = all 32 banks, 8 words/bank, balanced.
__global__ __launch_bounds__(256) void gemm_qkv(const u16* __restrict__ A,
    const u16* __restrict__ B, const float* __restrict__ bias,
    u16* __restrict__ qtg, u16* __restrict__ kg, u16* __restrict__ vtg) {
  __shared__ __align__(16) u16 at[128 * 64];
  __shared__ __align__(16) u16 bt[128 * 64];
  const int tid  = threadIdx.x;
  const int lane = tid & 63;
  const int w    = tid >> 6;
  const int quad = lane >> 4;
  const int col  = lane & 15;
  const int bid  = blockIdx.x;                       // 1152 blocks
  const int wgid = (bid & 7) * 144 + (bid >> 3);     // XCD-chunked, bijective
  const int n0 = (wgid % 18) * 128;
  const int m0 = (wgid / 18) * 128;
  const int lrow = lane >> 3;                        // 0..7 in gload group
  const int lchk = ((lane & 7) ^ lrow) * 8;          // swizzled source chunk
  const int wm = (w >> 1) * 64;
  const int wn = (w & 1) * 64;
  const int c7 = col & 7;

  const f4v fz = {0.f, 0.f, 0.f, 0.f};
  f4v acc[4][4];
#pragma unroll
  for (int i = 0; i < 4; i++)
#pragma unroll
    for (int j = 0; j < 4; j++) acc[i][j] = fz;

  // wave w stages A rows [w*32, w*32+32) via 4 gloads of 8 rows, B likewise
  const u16* ga = A + (size_t)(m0 + w * 32 + lrow) * NDIM + lchk;
  const u16* gb = B + (size_t)(n0 + w * 32 + lrow) * NDIM + lchk;
  u16* const la = at + (size_t)w * 2048;             // 32 rows x 64
  u16* const lb = bt + (size_t)w * 2048;

  for (int k0 = 0; k0 < NDIM; k0 += 64) {
    __syncthreads();                  // prior compute done reading LDS
    gload_lds16(ga + k0, la);
    gload_lds16(ga + (size_t)8 * NDIM + k0, la + 512);
    gload_lds16(ga + (size_t)16 * NDIM + k0, la + 1024);
    gload_lds16(ga + (size_t)24 * NDIM + k0, la + 1536);
    gload_lds16(gb + k0, lb);
    gload_lds16(gb + (size_t)8 * NDIM + k0, lb + 512);
    gload_lds16(gb + (size_t)16 * NDIM + k0, lb + 1024);
    gload_lds16(gb + (size_t)24 * NDIM + k0, lb + 1536);
    __syncthreads();                  // vmcnt drained -> tiles in LDS
#pragma unroll
    for (int kk = 0; kk < 2; kk++) {
      const int xo = ((kk * 4 + quad) ^ c7) * 8;
      s8v af[4], bf[4];
#pragma unroll
      for (int i = 0; i < 4; i++)
        af[i] = *(const s8v*)(at + (wm + i * 16 + col) * 64 + xo);
#pragma unroll
      for (int j = 0; j < 4; j++)
        bf[j] = *(const s8v*)(bt + (wn + j * 16 + col) * 64 + xo);
#pragma unroll
      for (int i = 0; i < 4; i++)
#pragma unroll
        for (int j = 0; j < 4; j++)
          acc[i][j] = __builtin_amdgcn_mfma_f32_16x16x32_bf16(af[i], bf[j], acc[i][j], 0, 0, 0);
    }
  }

  const int wmg = m0 + wm;
  const int wng = n0 + wn;
  const int s = n0 / NDIM;   // 0=q 1=k 2=v, block-uniform (768 = 6*128)
#pragma unroll
  for (int j = 0; j < 4; j++) {
    const int c = wng + j * 16 + col;
    const float bv = bias[c];
    const int r = c - s * NDIM;
    const int h = r >> 6;
    const int d = r & 63;
#pragma unroll
    for (int i = 0; i < 4; i++) {
      const int mb = wmg + i * 16 + quad * 4;   // 4 consecutive rows (regs)
      const int bb = mb >> 12;
      const int n  = mb & 4095;
      const size_t hb = (size_t)(bb * NH + h);
      const f4v v = acc[i][j];
      if (s == 2) {
        u16x4 pk;
#pragma unroll
        for (int rg = 0; rg < 4; rg++) pk[rg] = f2bf(v[rg] + bv);
        *(u16x4*)(vtg + (hb * HD + d) * SEQ + n) = pk;   // transposed store
      } else if (s == 0) {
        u16x4 pk;                                        // q transposed too
#pragma unroll
        for (int rg = 0; rg < 4; rg++) pk[rg] = f2bf((v[rg] + bv) * C1);
        *(u16x4*)(qtg + (hb * HD + d) * SEQ + n) = pk;
      } else {
#pragma unroll
        for (int rg = 0; rg < 4; rg++)
          kg[(hb * SEQ + (size_t)(n + rg)) * HD + d] = f2bf(v[rg] + bv);
      }
    }
  }
}

// ---------------- flash attention, 32x32 MFMA + in-register P (T12) ----------------
// R2/R4-verified structure (116.6us): K/V LDS double-buffered PSTR=72 panels,
// reg-staged, one barrier/iter, split-tile interleave, setprio. This round:
// st zero-init hoisted via persistent zacc C-operand (saves 32 v_mov/wave-iter
// on a ~47%-busy VALU; +16 VGPR, still under the 3-wave/SIMD cap).
__global__ __launch_bounds__(256, 3) void attn_kernel(const u16* __restrict__ qtg,
    const u16* __restrict__ kg, const u16* __restrict__ vtg, u16* __restrict__ og) {
  __shared__ __align__(16) u16 kls[2][64 * PSTR];   // [buf][key][64 d + 8 pad]
  __shared__ __align__(16) u16 vls[2][64 * PSTR];   // [buf][d row][64 keys + 8 pad]
  __shared__ float lws[4][32];                      // per-wave 1/l broadcast

  const int tid  = threadIdx.x;
  const int lane = tid & 63;
  const int w    = tid >> 6;
  const int hi   = lane >> 5;
  const int c    = lane & 31;
  // XCD swizzle: bh = blk % 24 -> all q-tiles of one (b,h) on one XCD.
  const int blk = blockIdx.x;
  const int bh  = blk % NBH;
  const int q0  = (blk / NBH) * 128;
  const size_t gbase = (size_t)bh * (SEQ * HD);
  const int wq = w * 32;           // this wave's 32 q rows

  // Q B-frags from transposed layout: qf[s][j] = Q[d=s*16+hi*8+j][q=q0+wq+c]
  s8v qf[4];
  {
    const u16* qp = qtg + gbase + (q0 + wq + c);
#pragma unroll
    for (int s = 0; s < 4; s++) {
      s8v t;
#pragma unroll
      for (int j = 0; j < 8; j++)
        t[j] = (short)qp[(size_t)(s * 16 + hi * 8 + j) * SEQ];
      qf[s] = t;
    }
  }

  f16x zacc;                       // persistent zero C-operand
#pragma unroll
  for (int e = 0; e < 16; e++) zacc[e] = 0.f;
  f16x o0 = zacc, o1 = zacc;       // O[q=32][d=0..31], O[q][d=32..63]
  float l0 = 0.f, l1 = 0.f, l2 = 0.f, l3 = 0.f;

  // staging: 8 lanes per row (row=tid>>3, chunk=(tid&7)*8), 2 passes of 32 rows
  const int srow8 = tid >> 3;        // 0..31
  const int sch8  = (tid & 7) * 8;   // 0..56
  const u16* kp = kg  + gbase + (size_t)srow8 * HD  + sch8;   // +(kb+32p)*HD
  const u16* vp = vtg + gbase + (size_t)srow8 * SEQ;          // +32p*SEQ +kb+sch8

  // prologue: tile 0 -> regs -> buf0
  s8v kr0 = *(const s8v*)(kp);
  s8v kr1 = *(const s8v*)(kp + (size_t)32 * HD);
  s8v vr0 = *(const s8v*)(vp + sch8);
  s8v vr1 = *(const s8v*)(vp + (size_t)32 * SEQ + sch8);
  *(s8v*)(kls[0] + srow8 * PSTR + sch8) = kr0;
  *(s8v*)(kls[0] + (32 + srow8) * PSTR + sch8) = kr1;
  *(s8v*)(vls[0] + srow8 * PSTR + sch8) = vr0;
  *(s8v*)(vls[0] + (32 + srow8) * PSTR + sch8) = vr1;

  for (int kb = 0; kb < SEQ; kb += 64) {
    const int cur = (kb >> 6) & 1;
    const u16* kt_ = kls[cur];
    const u16* vt_ = vls[cur];
    __syncthreads();               // buf[cur] ready; prev reads of buf[cur^1] done

    // issue next-tile global loads; in flight under the whole compute phase
    if (kb + 64 < SEQ) {
      kr0 = *(const s8v*)(kp + (size_t)(kb + 64) * HD);
      kr1 = *(const s8v*)(kp + (size_t)(kb + 96) * HD);
      vr0 = *(const s8v*)(vp + kb + 64 + sch8);
      vr1 = *(const s8v*)(vp + (size_t)32 * SEQ + kb + 64 + sch8);
    }

    // St = K @ Q^T: st0 = keys 0..31, st1 = keys 32..63 (rows), q = cols.
    // First MFMA consumes zacc (no per-iter zero-init).
    __builtin_amdgcn_s_setprio(1);
    f16x st0, st1;
    {
      const s8v k0_ = *(const s8v*)(kt_ + c * PSTR + hi * 8);
      const s8v k1_ = *(const s8v*)(kt_ + (32 + c) * PSTR + hi * 8);
      st0 = __builtin_amdgcn_mfma_f32_32x32x16_bf16(k0_, qf[0], zacc, 0, 0, 0);
      st1 = __builtin_amdgcn_mfma_f32_32x32x16_bf16(k1_, qf[0], zacc, 0, 0, 0);
    }
#pragma unroll
    for (int s = 1; s < 4; s++) {
      const s8v k0_ = *(const s8v*)(kt_ + c * PSTR + s * 16 + hi * 8);
      const s8v k1_ = *(const s8v*)(kt_ + (32 + c) * PSTR + s * 16 + hi * 8);
      st0 = __builtin_amdgcn_mfma_f32_32x32x16_bf16(k0_, qf[s], st0, 0, 0, 0);
      st1 = __builtin_amdgcn_mfma_f32_32x32x16_bf16(k1_, qf[s], st1, 0, 0, 0);
    }
    __builtin_amdgcn_s_setprio(0);

    // SM(st0): exp2 -> cvt_pk bf16 -> hi-half exchange -> PV A-frags pa0,pa1
    s8v pa0, pa1, pa2, pa3;
    {
      float p[16];
#pragma unroll
      for (int e = 0; e < 16; e++) p[e] = ex2(st0[e]);
      l0 += p[0] + p[4] + p[8]  + p[12];
      l1 += p[1] + p[5] + p[9]  + p[13];
      l2 += p[2] + p[6] + p[10] + p[14];
      l3 += p[3] + p[7] + p[11] + p[15];
      uint32_t k0 = cvtpk_bf16(p[0],  p[1]);
      uint32_t k1 = cvtpk_bf16(p[2],  p[3]);
      uint32_t k2 = cvtpk_bf16(p[4],  p[5]);
      uint32_t k3 = cvtpk_bf16(p[6],  p[7]);
      uint32_t k4 = cvtpk_bf16(p[8],  p[9]);
      uint32_t k5 = cvtpk_bf16(p[10], p[11]);
      uint32_t k6 = cvtpk_bf16(p[12], p[13]);
      uint32_t k7 = cvtpk_bf16(p[14], p[15]);
      pl32swap(k0, k2); pl32swap(k1, k3);   // -> slots 0..3 of ks=0
      pl32swap(k4, k6); pl32swap(k5, k7);   // -> slots 0..3 of ks=1
      u32x4v wA = {k0, k1, k2, k3};
      u32x4v wB = {k4, k5, k6, k7};
      pa0 = __builtin_bit_cast(s8v, wA);
      pa1 = __builtin_bit_cast(s8v, wB);
    }

    // PV ks=0,1 (keys 0..31) — overlaps SM(st1) below
    __builtin_amdgcn_s_setprio(1);
    {
      const s8v v00 = *(const s8v*)(vt_ + c * PSTR + hi * 8);
      const s8v v01 = *(const s8v*)(vt_ + (32 + c) * PSTR + hi * 8);
      const s8v v10 = *(const s8v*)(vt_ + c * PSTR + 16 + hi * 8);
      const s8v v11 = *(const s8v*)(vt_ + (32 + c) * PSTR + 16 + hi * 8);
      o0 = __builtin_amdgcn_mfma_f32_32x32x16_bf16(pa0, v00, o0, 0, 0, 0);
      o1 = __builtin_amdgcn_mfma_f32_32x32x16_bf16(pa0, v01, o1, 0, 0, 0);
      o0 = __builtin_amdgcn_mfma_f32_32x32x16_bf16(pa1, v10, o0, 0, 0, 0);
      o1 = __builtin_amdgcn_mfma_f32_32x32x16_bf16(pa1, v11, o1, 0, 0, 0);
    }
    __builtin_amdgcn_s_setprio(0);

    // SM(st1) -> pa2,pa3 (VALU/TRANS, overlaps PV cluster above)
    {
      float p[16];
#pragma unroll
      for (int e = 0; e < 16; e++) p[e] = ex2(st1[e]);
      l0 += p[0] + p[4] + p[8]  + p[12];
      l1 += p[1] + p[5] + p[9]  + p[13];
      l2 += p[2] + p[6] + p[10] + p[14];
      l3 += p[3] + p[7] + p[11] + p[15];
      uint32_t k0 = cvtpk_bf16(p[0],  p[1]);
      uint32_t k1 = cvtpk_bf16(p[2],  p[3]);
      uint32_t k2 = cvtpk_bf16(p[4],  p[5]);
      uint32_t k3 = cvtpk_bf16(p[6],  p[7]);
      uint32_t k4 = cvtpk_bf16(p[8],  p[9]);
      uint32_t k5 = cvtpk_bf16(p[10], p[11]);
      uint32_t k6 = cvtpk_bf16(p[12], p[13]);
      uint32_t k7 = cvtpk_bf16(p[14], p[15]);
      pl32swap(k0, k2); pl32swap(k1, k3);
      pl32swap(k4, k6); pl32swap(k5, k7);
      u32x4v wA = {k0, k1, k2, k3};
      u32x4v wB = {k4, k5, k6, k7};
      pa2 = __builtin_bit_cast(s8v, wA);
      pa3 = __builtin_bit_cast(s8v, wB);
    }

    // stage next tile NOW: ds_write lgkm drains under the PV cluster below.
    if (kb + 64 < SEQ) {
      u16* kn = (u16*)kls[cur ^ 1];
      u16* vn = (u16*)vls[cur ^ 1];
      *(s8v*)(kn + srow8 * PSTR + sch8) = kr0;
      *(s8v*)(kn + (32 + srow8) * PSTR + sch8) = kr1;
      *(s8v*)(vn + srow8 * PSTR + sch8) = vr0;
      *(s8v*)(vn + (32 + srow8) * PSTR + sch8) = vr1;
    }

    // PV ks=2,3 (keys 32..63)
    __builtin_amdgcn_s_setprio(1);
    {
      const s8v v20 = *(const s8v*)(vt_ + c * PSTR + 32 + hi * 8);
      const s8v v21 = *(const s8v*)(vt_ + (32 + c) * PSTR + 32 + hi * 8);
      const s8v v30 = *(const s8v*)(vt_ + c * PSTR + 48 + hi * 8);
      const s8v v31 = *(const s8v*)(vt_ + (32 + c) * PSTR + 48 + hi * 8);
      o0 = __builtin_amdgcn_mfma_f32_32x32x16_bf16(pa2, v20, o0, 0, 0, 0);
      o1 = __builtin_amdgcn_mfma_f32_32x32x16_bf16(pa2, v21, o1, 0, 0, 0);
      o0 = __builtin_amdgcn_mfma_f32_32x32x16_bf16(pa3, v30, o0, 0, 0, 0);
      o1 = __builtin_amdgcn_mfma_f32_32x32x16_bf16(pa3, v31, o1, 0, 0, 0);
    }
    __builtin_amdgcn_s_setprio(0);
  }

  // epilogue: l[q=c] lives column-indexed; O rows are q -> broadcast 1/l via
  // tiny per-wave LDS (wave-private region, broadcast reads)
  float lt = l0 + l1 + l2 + l3;
  lt += __shfl_xor(lt, 32);
  const float inv = 1.0f / lt;
  if (hi == 0) lws[w][c] = inv;

  const int b = bh / NH;
  const int h = bh % NH;
  u16* obase = og + (size_t)(b * SEQ + q0 + wq) * NDIM + h * HD + c;
#pragma unroll
  for (int r = 0; r < 16; r++) {
    const int row = (r & 3) + 8 * (r >> 2) + 4 * hi;   // q offset in wave tile
    const float invr = lws[w][row];                     // broadcast read
    u16* rp = obase + (size_t)row * NDIM;
    rp[0]  = f2bf(o0[r] * invr);
    rp[32] = f2bf(o1[r] * invr);
  }
}

// ---------------- proj GEMM: out[8192,768] = attn @ proj_w^T + b (fp32 out) ----
// Same BK=64 staging as gemm_qkv; bijective XCD swizzle (384 % 8 == 0).
__global__ __launch_bounds__(256) void gemm_proj(const u16* __restrict__ A,
    const u16* __restrict__ B, const float* __restrict__ bias, float* __restrict__ out) {
  __shared__ __align__(16) u16 at[128 * 64];
  __shared__ __align__(16) u16 bt[128 * 64];
  const int tid  = threadIdx.x;
  const int lane = tid & 63;
  const int w    = tid >> 6;
  const int quad = lane >> 4;
  const int col  = lane & 15;
  const int bid  = blockIdx.x;                       // 384 blocks
  const int wgid = (bid & 7) * 48 + (bid >> 3);
  const int n0 = (wgid % 6) * 128;
  const int m0 = (wgid / 6) * 128;
  const int lrow = lane >> 3;
  const int lchk = ((lane & 7) ^ lrow) * 8;
  const int wm = (w >> 1) * 64;
  const int wn = (w & 1) * 64;
  const int c7 = col & 7;

  const f4v fz = {0.f, 0.f, 0.f, 0.f};
  f4v acc[4][4];
#pragma unroll
  for (int i = 0; i < 4; i++)
#pragma unroll
    for (int j = 0; j < 4; j++) acc[i][j] = fz;

  const u16* ga = A + (size_t)(m0 + w * 32 + lrow) * NDIM + lchk;
  const u16* gb = B + (size_t)(n0 + w * 32 + lrow) * NDIM + lchk;
  u16* const la = at + (size_t)w * 2048;
  u16* const lb = bt + (size_t)w * 2048;

  for (int k0 = 0; k0 < NDIM; k0 += 64) {
    __syncthreads();
    gload_lds16(ga + k0, la);
    gload_lds16(ga + (size_t)8 * NDIM + k0, la + 512);
    gload_lds16(ga + (size_t)16 * NDIM + k0, la + 1024);
    gload_lds16(ga + (size_t)24 * NDIM + k0, la + 1536);
    gload_lds16(gb + k0, lb);
    gload_lds16(gb + (size_t)8 * NDIM + k0, lb + 512);
    gload_lds16(gb + (size_t)16 * NDIM + k0, lb + 1024);
    gload_lds16(gb + (size_t)24 * NDIM + k0, lb + 1536);
    __syncthreads();
#pragma unroll
    for (int kk = 0; kk < 2; kk++) {
      const int xo = ((kk * 4 + quad) ^ c7) * 8;
      s8v af[4], bf[4];
#pragma unroll
      for (int i = 0; i < 4; i++)
        af[i] = *(const s8v*)(at + (wm + i * 16 + col) * 64 + xo);
#pragma unroll
      for (int j = 0; j < 4; j++)
        bf[j] = *(const s8v*)(bt + (wn + j * 16 + col) * 64 + xo);
#pragma unroll
      for (int i = 0; i < 4; i++)
#pragma unroll
        for (int j = 0; j < 4; j++)
          acc[i][j] = __builtin_amdgcn_mfma_f32_16x16x32_bf16(af[i], bf[j], acc[i][j], 0, 0, 0);
    }
  }

  const int wmg = m0 + wm;
  const int wng = n0 + wn;
#pragma unroll
  for (int j = 0; j < 4; j++) {
    const int c = wng + j * 16 + col;
    const float bv = bias[c];
#pragma unroll
    for (int i = 0; i < 4; i++) {
#pragma unroll
      for (int rg = 0; rg < 4; rg++)
        out[(size_t)(wmg + i * 16 + quad * 4 + rg) * NDIM + c] = acc[i][j][rg] + bv;
    }
  }
}

// ---------------- launch ----------------
extern "C" void kernel_launch(void* const* d_in, const int* in_sizes, int n_in,
                              void* d_out, int out_size, void* d_ws, size_t ws_size,
                              hipStream_t stream) {
  const float* x      = (const float*)d_in[0];
  const float* qkv_w  = (const float*)d_in[1];
  const float* qkv_b  = (const float*)d_in[2];
  const float* proj_w = (const float*)d_in[3];
  const float* proj_b = (const float*)d_in[4];
  float* out = (float*)d_out;

  u16* ws   = (u16*)d_ws;
  u16* x_bf = ws;                              // 8192*768
  u16* wq   = x_bf + (size_t)MTOT * NDIM;      // 2304*768
  u16* wp   = wq + (size_t)3 * NDIM * NDIM;    // 768*768
  u16* qt   = wp + (size_t)NDIM * NDIM;        // 24*64*4096 (transposed q)
  u16* k_bf = qt + (size_t)NBH * SEQ * HD;
  u16* vt   = k_bf + (size_t)NBH * SEQ * HD;
  u16* a_bf = vt + (size_t)NBH * SEQ * HD;     // 8192*768

  const int nx = MTOT * NDIM / 4, nw1 = 3 * NDIM * NDIM / 4, nw2 = NDIM * NDIM / 4;
  const int ntot = nx + nw1 + nw2;
  cvt3_kernel<<<(ntot + 255) / 256, 256, 0, stream>>>(x, x_bf, nx, qkv_w, wq, nw1,
                                                      proj_w, wp, nw2);

  gemm_qkv<<<1152, 256, 0, stream>>>(x_bf, wq, qkv_b, qt, k_bf, vt);
  attn_kernel<<<768, 256, 0, stream>>>(qt, k_bf, vt, a_bf);
  gemm_proj<<<384, 256, 0, stream>>>(a_bf, wp, proj_b, out);
}